// Round 6
// baseline (3714.095 us; speedup 1.0000x reference)
//
#include <hip/hip_runtime.h>
#include <math.h>

// ---------------------------------------------------------------------------
// DelayRNN persistent kernel, R16: BATCH-PARALLEL, zero inter-block sync.
// Rounds 0-5 post-mortem: the model's recurrence is per-batch independent --
// h, delay-gate, memory events, decoder are all batch-local; only weights are
// shared (read-only). The column-split design forced cross-block h exchange
// (flags, MALL hops, coherent reloads) = the 11.7us/step floor. R16 assigns
// one batch per block (32 blocks, 512 thr): all state lives in LDS, weights
// stream from L2 (same lines for all blocks on an XCD -> resident).
//  * mem events: LDS mem[160][64]; event e from enc step s, gate d:
//    c=s+1+d; c<128 -> e=c; else rr=c-129, rr even && rr/2<32 -> e=128+rr/2
//    (mapping validated in R11/R13). d=0 flows through the SAME path (write
//    mem[s+1] before step s+1 reads it) -- no sel-correction special case.
//  * lin = elu(concat(x,mem)@W_e1 + b_e1); gi = lin@W2 + B2 with
//    W2=W_e2@W_ih, B2=b_e2@W_ih+b_ih (precomputed in ws, validated).
//  * decode: x=0, DG skipped (events would be zero), F1/F2 in-block.
// Init: cooperative W2/B2 + one gridbar; then fully independent blocks.
// ---------------------------------------------------------------------------

#define kB 32
#define kT 128
#define kI 64
#define kH 256
#define kD 32
#define kC 64
#define kOut 32
#define kSteps (kT + kOut)            // 160
#define NB 32
#define NTHR 512
#define NT_ALL (NB * NTHR)

// ws float offsets. Zeroed region: [0, 1856) (gridbar counter at [320]).
#define WS_W2 1856                     // W2 = W_e2@W_ih [256][768]
#define WS_B2 (WS_W2 + kH * 3 * kH)    // B2 [768]
#define WS_ZERO_BYTES ((size_t)1856 * sizeof(float))

// ---- Threefry-2x32 (jax partitionable path) ----
__device__ __forceinline__ void tf2x32(unsigned k0, unsigned k1,
                                       unsigned x0, unsigned x1,
                                       unsigned& o0, unsigned& o1) {
  unsigned ks2 = k0 ^ k1 ^ 0x1BD11BDAu;
  unsigned v0 = x0 + k0, v1 = x1 + k1;
#define TFR(r) { v0 += v1; v1 = (v1 << (r)) | (v1 >> (32-(r))); v1 ^= v0; }
  TFR(13) TFR(15) TFR(26) TFR(6)   v0 += k1;  v1 += ks2 + 1u;
  TFR(17) TFR(29) TFR(16) TFR(24)  v0 += ks2; v1 += k0  + 2u;
  TFR(13) TFR(15) TFR(26) TFR(6)   v0 += k0;  v1 += k1  + 3u;
  TFR(17) TFR(29) TFR(16) TFR(24)  v0 += k1;  v1 += ks2 + 4u;
  TFR(13) TFR(15) TFR(26) TFR(6)   v0 += ks2; v1 += k0  + 5u;
#undef TFR
  o0 = v0; o1 = v1;
}
__device__ __forceinline__ float bits_to_gumbel(unsigned bits) {
  float f = __uint_as_float((bits >> 9) | 0x3F800000u) - 1.0f;
  float u = f + 1.17549435e-38f;
  return -logf(-logf(u));
}

__device__ __forceinline__ void gridbar_full(unsigned* u, unsigned target) {
  __syncthreads();
  if (threadIdx.x == 0) {
    __threadfence();
    __hip_atomic_fetch_add(&u[320], 1u, __ATOMIC_ACQ_REL, __HIP_MEMORY_SCOPE_AGENT);
    while (__hip_atomic_load(&u[320], __ATOMIC_RELAXED, __HIP_MEMORY_SCOPE_AGENT) < target)
      __builtin_amdgcn_s_sleep(1);
    __threadfence();
  }
  __syncthreads();
}

__device__ __forceinline__ float elu1(float v) { return v > 0.f ? v : expm1f(v); }

__global__ __launch_bounds__(NTHR)
void delay_rnn(const float* __restrict__ x, const int* __restrict__ lengths,
               const float* __restrict__ W_dg1, const float* __restrict__ b_dg1,
               const float* __restrict__ W_dg2, const float* __restrict__ b_dg2,
               const float* __restrict__ W_e1,  const float* __restrict__ b_e1,
               const float* __restrict__ W_e2,  const float* __restrict__ b_e2,
               const float* __restrict__ W_ih,  const float* __restrict__ b_ih,
               const float* __restrict__ W_hh,  const float* __restrict__ b_hh,
               const float* __restrict__ W_f1,  const float* __restrict__ b_f1,
               const float* __restrict__ W_f2,  const float* __restrict__ b_f2,
               float* __restrict__ out, float* __restrict__ ws) {
  const int tid = threadIdx.x;
  const int bid = blockIdx.x;
  const int gid = bid * NTHR + tid;

  float* W2g = ws + WS_W2;
  float* B2g = ws + WS_B2;

  // ---------------- cooperative init: W2 = W_e2@W_ih, B2 ----------------
  for (int idx = gid; idx < kH * 3 * kH; idx += NT_ALL) {
    int k = idx / (3 * kH), n = idx % (3 * kH);
    const float* wr = W_e2 + k * kH;
    float s0 = 0, s1 = 0, s2 = 0, s3 = 0;
    for (int m = 0; m < kH; m += 4) {
      float4 wv = *(const float4*)(wr + m);
      s0 += wv.x * W_ih[(m    ) * 3 * kH + n];
      s1 += wv.y * W_ih[(m + 1) * 3 * kH + n];
      s2 += wv.z * W_ih[(m + 2) * 3 * kH + n];
      s3 += wv.w * W_ih[(m + 3) * 3 * kH + n];
    }
    W2g[idx] = ((s0 + s1) + (s2 + s3));
  }
  for (int n = gid; n < 3 * kH; n += NT_ALL) {
    float s = b_ih[n];
    for (int m = 0; m < kH; ++m) s += b_e2[m] * W_ih[m * 3 * kH + n];
    B2g[n] = s;
  }
  gridbar_full((unsigned*)ws, NB);   // only cross-block sync in the kernel

  // ---------------- block-local state (batch b = bid) ----------------
  __shared__ float memL[kSteps * kI];   // 10240 f: future mem events
  __shared__ float gL[kT * kD];         // 4096 f: gumbel slice for this batch
  __shared__ float ghgi[6 * kH];        // 1536 f: [gh r,z,n | gi r,z,n][256]
  __shared__ float hL[kH], linL[kH], o1L[kH];
  __shared__ float xL[kI], l1s[kD], lgL[kD], decT[kD];
  __shared__ int   selE, selD, lenS;

  for (int i = tid; i < kSteps * kI; i += NTHR) memL[i] = 0.f;
  {
    unsigned k0, k1; tf2x32(0u, 42u, 0u, 0u, k0, k1);
    for (int i = tid; i < kT * kD; i += NTHR) {
      int s = i >> 5, j = i & 31;
      unsigned a, b;
      tf2x32(k0, k1, 0u, (unsigned)(s * 1024 + bid * 32 + j), a, b);
      gL[i] = bits_to_gumbel(a ^ b);   // = g[(s*32+b)*32+j], R11-validated
    }
  }
  for (int i = tid; i < kH; i += NTHR) hL[i] = 0.f;
  if (tid < kD) decT[tid] = powf(0.99f, (float)(tid + 1));
  if (tid == 0) lenS = lengths[bid];
  __syncthreads();

  // ---------------- sequential per-batch recurrence ----------------
  for (int s = 0; s < kSteps; ++s) {
    const bool enc = (s < kT);

    // phase 1: stage x_t (encode only; decode x=0 and unused)
    if (enc) {
      if (tid < kI) xL[tid] = x[(bid * kT + s) * kI + tid];
      __syncthreads();
    }

    // phase 2: lin = elu(concat(x,mem_s)@W_e1 + b_e1)   [t<256]
    //          DG layer-1 = elu(concat(x,h)@W_dg1+b)     [256<=t<288, enc]
    if (tid < kH) {
      const int j = tid;
      float a = b_e1[j];
      if (enc) {
        #pragma unroll 4
        for (int k = 0; k < kI; ++k) a += xL[k] * W_e1[k * kH + j];
      }
      const float* mrow = memL + s * kI;
      #pragma unroll 4
      for (int k = 0; k < kI; ++k) a += mrow[k] * W_e1[(kI + k) * kH + j];
      linL[j] = elu1(a);
    } else if (enc && tid < kH + kD) {
      const int j = tid - kH;
      float a = b_dg1[j];
      #pragma unroll 4
      for (int k = 0; k < 320; ++k) {
        float cv = (k < kI) ? xL[k] : hL[k - kI];
        a += cv * W_dg1[k * kD + j];
      }
      l1s[j] = elu1(a);
    }
    __syncthreads();

    // phase 3: main GEMV pair, f4 columns [t<384]; dg2+gumbel [384..415, enc]
    if (tid < 384) {
      const bool isGH = (tid < 192);
      const int col = (isGH ? tid : tid - 192) * 4;
      const float* W = (isGH ? W_hh : W2g) + col;
      const float* v = isGH ? hL : linL;
      float ax = 0.f, ay = 0.f, az = 0.f, aw = 0.f;
      #pragma unroll 8
      for (int k = 0; k < kH; ++k) {
        float4 w = *(const float4*)(W + k * 768);
        float vv = v[k];
        ax += vv * w.x; ay += vv * w.y; az += vv * w.z; aw += vv * w.w;
      }
      const float* bb = isGH ? (b_hh + col) : (B2g + col);
      float4 r;
      r.x = ax + bb[0]; r.y = ay + bb[1]; r.z = az + bb[2]; r.w = aw + bb[3];
      *(float4*)&ghgi[(isGH ? 0 : 768) + col] = r;
    } else if (enc && tid < 384 + kD) {
      const int j = tid - 384;
      float sv = b_dg2[j];
      #pragma unroll
      for (int k = 0; k < kD; ++k) sv += l1s[k] * W_dg2[k * kD + j];
      lgL[j] = sv + gL[s * kD + j];
    }
    __syncthreads();

    // phase 4: gate math + h update [t<256]; argmax+event target [t==256, enc]
    if (tid < kH) {
      const int j = tid;
      float ghr = ghgi[j], ghz = ghgi[256 + j], ghn = ghgi[512 + j];
      float gir = ghgi[768 + j], giz = ghgi[1024 + j], gin = ghgi[1280 + j];
      float r = 1.f / (1.f + expf(-(gir + ghr)));
      float z = 1.f / (1.f + expf(-(giz + ghz)));
      float n = tanhf(gin + r * ghn);
      float hold = hL[j];
      float nh = (1.f - z) * n + z * hold;
      hL[j] = enc ? ((s < lenS) ? nh : hold) : nh;
    } else if (enc && tid == kH) {
      float best = lgL[0]; int d = 0;
      for (int j = 1; j < kD; ++j) {
        float v2 = lgL[j];
        if (v2 > best) { best = v2; d = j; }
      }
      int c = s + 1 + d, e = -1;
      if (c < kT) e = c;
      else { int rr = c - kT - 1;
             if (rr >= 0 && !(rr & 1)) { int kk = rr >> 1; if (kk < kOut) e = kT + kk; } }
      selE = e; selD = d;
    }
    __syncthreads();

    // phase 5: encode -> memory event; decode -> F1/F2 output head
    if (enc) {
      if (tid < kI) {
        int e = selE;
        if (e >= 0) memL[e * kI + tid] += decT[selD] * xL[tid];
      }
      __syncthreads();   // orders event write vs next step's mem read (also s=127 -> s=128)
    } else {
      if (tid < kH) {
        const int j = tid;
        float a = b_f1[j];
        #pragma unroll 4
        for (int k = 0; k < kH; ++k) a += hL[k] * W_f1[k * kH + j];
        o1L[j] = a > 0.f ? a : 0.f;
      }
      __syncthreads();
      if (tid < kC) {
        const int j = tid;
        float v2 = b_f2[j];
        #pragma unroll 4
        for (int k = 0; k < kH; ++k) v2 += o1L[k] * W_f2[k * kC + j];
        out[(bid * kOut + (s - kT)) * kC + j] = v2;
      }
      __syncthreads();
    }
  }
}

extern "C" void kernel_launch(void* const* d_in, const int* in_sizes, int n_in,
                              void* d_out, int out_size, void* d_ws, size_t ws_size,
                              hipStream_t stream) {
  (void)in_sizes; (void)n_in; (void)out_size; (void)ws_size;
  const float* x      = (const float*)d_in[0];
  const int*   lens   = (const int*)  d_in[1];
  const float* W_dg1  = (const float*)d_in[3];
  const float* b_dg1  = (const float*)d_in[4];
  const float* W_dg2  = (const float*)d_in[5];
  const float* b_dg2  = (const float*)d_in[6];
  const float* W_e1   = (const float*)d_in[7];
  const float* b_e1   = (const float*)d_in[8];
  const float* W_e2   = (const float*)d_in[9];
  const float* b_e2   = (const float*)d_in[10];
  const float* W_ih   = (const float*)d_in[11];
  const float* b_ih   = (const float*)d_in[12];
  const float* W_hh   = (const float*)d_in[13];
  const float* b_hh   = (const float*)d_in[14];
  const float* W_f1   = (const float*)d_in[15];
  const float* b_f1   = (const float*)d_in[16];
  const float* W_f2   = (const float*)d_in[17];
  const float* b_f2   = (const float*)d_in[18];

  hipMemsetAsync(d_ws, 0, WS_ZERO_BYTES, stream);
  delay_rnn<<<dim3(NB), dim3(NTHR), 0, stream>>>(
      x, lens, W_dg1, b_dg1, W_dg2, b_dg2, W_e1, b_e1, W_e2, b_e2,
      W_ih, b_ih, W_hh, b_hh, W_f1, b_f1, W_f2, b_f2,
      (float*)d_out, (float*)d_ws);
}

// Round 7
// 2393.222 us; speedup vs baseline: 1.5519x; 1.5519x over previous
//
#include <hip/hip_runtime.h>
#include <math.h>

// ---------------------------------------------------------------------------
// DelayRNN persistent kernel, R17: column-split GEMM, single-hop chain.
// R16 post-mortem: batch-per-block = per-CU weight streaming bound (1.6MB/step
// through one CU's L2 port ~ 12us) -> 22.8us/step. Column-split keeps weights
// LDS-resident; the cost is the h all-gather. R17 reduces the R11 4-role chain
// to JUST that h-hop:
//  * E1 eliminated algebraically (R13/R16-validated): lin(e) = linF[e]
//    (init: x_e@W_e1[0:64]+b_e1) + events decay[d]*P[s'], P = x@W_e1[64:128].
//  * DG distributed: GRU block b owns batch b's delay-gate (dg1/dg2/argmax
//    ~0.3us) computed after its h-update. NO DG role, NO DG/sel flags.
//  * d=0 events unified through linF[s+1] (R16-validated mapping): owner
//    writes the AXPY BEFORE its h-flag; readers of row s+1 wait on that flag
//    anyway -> ordering free, no sel-correction path in the GEMM.
//  * Single publish/block/step. GRU start-poll: 32 h-flags (+F1 WAR s>=132).
//  * Event writer exclusivity: linF[.][b] written only by block b -> no races.
// Blocks: 32 GRU | 16 F1 | 8 F2 = 56. Flags: FL[bid] for all roles.
// Pacing:
//   GRU_s : FL_H(all)>=s, FL_F1>=s-2 [s>=132]        (s in 0..159)
//   F1_s  : FL_H(all)>=s, FL_F2>=s-2 [s>=133]        (s in 129..160)
//   F2_s  : FL_F1(all)>=s                             (s in 130..161)
// ---------------------------------------------------------------------------

#define kB 32
#define kT 128
#define kI 64
#define kH 256
#define kD 32
#define kC 64
#define kOut 32
#define kSteps (kT + kOut)            // 160
#define NB 56
#define NTHR 256
#define NT_ALL (NB * NTHR)

// ws float offsets. Zeroed region: [0, WS_NZ)
#define WS_FL    384                   // int flags FL[56] @ stride 16 ints
#define WS_H     1856                  // h[4][32][256]
#define WS_NZ    (WS_H + 4*8192)       // end of zero region
#define WS_W2    WS_NZ                 // W2 = W_e2@W_ih [256][768]
#define WS_B2    (WS_W2 + kH*3*kH)     // B2 [768]
#define WS_G     (WS_B2 + 3*kH)        // gumbel [T*B*D]
#define WS_P     (WS_G + kT*kB*kD)     // P[s][b][j] = x_s @ W_e1[64:128]
#define WS_LINF  (WS_P + kT*kB*kH)     // linF[e][b][j] = x_e@W_e1[0:64]+b_e1 (+events)
#define WS_O1    (WS_LINF + kSteps*kB*kH) // o1[4][32][256]
#define WS_ZERO_BYTES ((size_t)WS_NZ * sizeof(float))

// ---- coherent scalar access (agent scope, L3 coherence point) ----
__device__ __forceinline__ float cload(const float* p) {
  return __hip_atomic_load(p, __ATOMIC_RELAXED, __HIP_MEMORY_SCOPE_AGENT);
}
__device__ __forceinline__ void cstore(float* p, float v) {
  __hip_atomic_store(p, v, __ATOMIC_RELAXED, __HIP_MEMORY_SCOPE_AGENT);
}
__device__ __forceinline__ int cload_i(const int* p) {
  return __hip_atomic_load(p, __ATOMIC_RELAXED, __HIP_MEMORY_SCOPE_AGENT);
}
__device__ __forceinline__ void cstore_i(int* p, int v) {
  __hip_atomic_store(p, v, __ATOMIC_RELAXED, __HIP_MEMORY_SCOPE_AGENT);
}
__device__ __forceinline__ float4 cload4(const float* p) {
  float4 r;
  asm volatile("global_load_dwordx4 %0, %1, off sc0 sc1" : "=v"(r) : "v"(p));
  return r;
}
__device__ __forceinline__ void cstore4(float* p, float4 v) {
  cstore(p + 0, v.x); cstore(p + 1, v.y);
  cstore(p + 2, v.z); cstore(p + 3, v.w);
}
__device__ __forceinline__ void waitvm() {
  asm volatile("s_waitcnt vmcnt(0)" ::: "memory");
}

// ---- flag sync ----
// FL[i]: i<32 GRU-h | 32..47 F1 | 48..55 F2.
__device__ __forceinline__ void poll(const int* FL, int tid,
                                     int tH, int tF1, int tF2) {
  int thr;
  if      (tid < 32) thr = tH;
  else if (tid < 48) thr = tF1;
  else if (tid < 56) thr = tF2;
  else thr = 0;
  const int* p = FL + tid * 16;
  for (;;) {
    int ok = (thr <= 0) || (cload_i(p) >= thr);
    if (__syncthreads_count(ok) == NTHR) return;
    __builtin_amdgcn_s_sleep(2);
  }
}
// Publish: all data stores drained per-wave, then block-sync, then flag store.
__device__ __forceinline__ void setflag(int* FL, int tid, int idx, int val) {
  waitvm();
  __syncthreads();
  if (tid == 0) cstore_i(FL + idx * 16, val);
}

// ---- Threefry-2x32 (jax partitionable path) ----
__device__ __forceinline__ void tf2x32(unsigned k0, unsigned k1,
                                       unsigned x0, unsigned x1,
                                       unsigned& o0, unsigned& o1) {
  unsigned ks2 = k0 ^ k1 ^ 0x1BD11BDAu;
  unsigned v0 = x0 + k0, v1 = x1 + k1;
#define TFR(r) { v0 += v1; v1 = (v1 << (r)) | (v1 >> (32-(r))); v1 ^= v0; }
  TFR(13) TFR(15) TFR(26) TFR(6)   v0 += k1;  v1 += ks2 + 1u;
  TFR(17) TFR(29) TFR(16) TFR(24)  v0 += ks2; v1 += k0  + 2u;
  TFR(13) TFR(15) TFR(26) TFR(6)   v0 += k0;  v1 += k1  + 3u;
  TFR(17) TFR(29) TFR(16) TFR(24)  v0 += k1;  v1 += ks2 + 4u;
  TFR(13) TFR(15) TFR(26) TFR(6)   v0 += ks2; v1 += k0  + 5u;
#undef TFR
  o0 = v0; o1 = v1;
}
__device__ __forceinline__ float bits_to_gumbel(unsigned bits) {
  float f = __uint_as_float((bits >> 9) | 0x3F800000u) - 1.0f;
  float u = f + 1.17549435e-38f;
  return -logf(-logf(u));
}

__device__ __forceinline__ void gridbar_full(unsigned* u, unsigned target) {
  __syncthreads();
  if (threadIdx.x == 0) {
    __threadfence();
    __hip_atomic_fetch_add(&u[320], 1u, __ATOMIC_ACQ_REL, __HIP_MEMORY_SCOPE_AGENT);
    while (__hip_atomic_load(&u[320], __ATOMIC_RELAXED, __HIP_MEMORY_SCOPE_AGENT) < target)
      __builtin_amdgcn_s_sleep(1);
    __threadfence();
  }
  __syncthreads();
}

__device__ __forceinline__ float elu1(float v) { return v > 0.f ? v : expm1f(v); }

__global__ __launch_bounds__(NTHR)
void delay_rnn(const float* __restrict__ x, const int* __restrict__ lengths,
               const float* __restrict__ W_dg1, const float* __restrict__ b_dg1,
               const float* __restrict__ W_dg2, const float* __restrict__ b_dg2,
               const float* __restrict__ W_e1,  const float* __restrict__ b_e1,
               const float* __restrict__ W_e2,  const float* __restrict__ b_e2,
               const float* __restrict__ W_ih,  const float* __restrict__ b_ih,
               const float* __restrict__ W_hh,  const float* __restrict__ b_hh,
               const float* __restrict__ W_f1,  const float* __restrict__ b_f1,
               const float* __restrict__ W_f2,  const float* __restrict__ b_f2,
               float* __restrict__ out, float* __restrict__ ws) {
  const int tid = threadIdx.x;
  const int bid = blockIdx.x;
  const int gid = bid * NTHR + tid;

  unsigned* baru = (unsigned*)ws;
  int*   FL    = (int*)(ws + WS_FL);
  float* hBuf  = ws + WS_H;
  float* W2g   = ws + WS_W2;
  float* B2g   = ws + WS_B2;
  float* g     = ws + WS_G;
  float* Pg    = ws + WS_P;
  float* linF  = ws + WS_LINF;
  float* o1B   = ws + WS_O1;

  __shared__ float S[36288];           // role-carved (max: GRU + dgred)
  __shared__ float sb1[32], sb2[32], decT[32];
  __shared__ float l1s[32], lgL[32], sXb[64];
  __shared__ int   len_s[32], selE, selD;

  // ---------------- init: gumbel, W2 = W_e2@W_ih, B2, P, linF ----------
  {
    unsigned k0, k1;
    tf2x32(0u, 42u, 0u, 0u, k0, k1);
    for (int i = gid; i < kT * kB * kD; i += NT_ALL) {
      unsigned a, b;
      tf2x32(k0, k1, 0u, (unsigned)i, a, b);
      g[i] = bits_to_gumbel(a ^ b);
    }
  }
  for (int idx = gid; idx < kH * 3 * kH; idx += NT_ALL) {
    int k = idx / (3 * kH), n = idx % (3 * kH);
    const float* wr = W_e2 + k * kH;
    float s0 = 0, s1 = 0, s2 = 0, s3 = 0;
    for (int m = 0; m < kH; m += 4) {
      float4 wv = *(const float4*)(wr + m);
      s0 += wv.x * W_ih[(m    ) * 3 * kH + n];
      s1 += wv.y * W_ih[(m + 1) * 3 * kH + n];
      s2 += wv.z * W_ih[(m + 2) * 3 * kH + n];
      s3 += wv.w * W_ih[(m + 3) * 3 * kH + n];
    }
    W2g[idx] = ((s0 + s1) + (s2 + s3));
  }
  for (int n = gid; n < 3 * kH; n += NT_ALL) {
    float s = b_ih[n];
    for (int m = 0; m < kH; ++m) s += b_e2[m] * W_ih[m * 3 * kH + n];
    B2g[n] = s;
  }
  // P[s][b][j] = sum_k x[b,s,k] * W_e1[64+k][j]  (mem-part weights)
  for (int idx = gid; idx < kT * kB * kH; idx += NT_ALL) {
    int s = idx >> 13, r = idx & 8191, b = r >> 8, j = r & 255;
    const float* xr = x + (b * kT + s) * kI;
    float a0 = 0, a1 = 0, a2 = 0, a3 = 0;
    for (int k = 0; k < 64; k += 4) {
      float4 xv = *(const float4*)(xr + k);
      a0 += xv.x * W_e1[(64 + k) * 256 + j];
      a1 += xv.y * W_e1[(65 + k) * 256 + j];
      a2 += xv.z * W_e1[(66 + k) * 256 + j];
      a3 += xv.w * W_e1[(67 + k) * 256 + j];
    }
    Pg[idx] = ((a0 + a1) + (a2 + a3));
  }
  // linF[e][b][j] = b_e1[j] + (e<kT ? x_e @ W_e1[0:64] : 0)
  for (int idx = gid; idx < kSteps * kB * kH; idx += NT_ALL) {
    int e = idx >> 13, r = idx & 8191, b = r >> 8, j = r & 255;
    float v = b_e1[j];
    if (e < kT) {
      const float* xr = x + (b * kT + e) * kI;
      float a0 = 0, a1 = 0, a2 = 0, a3 = 0;
      for (int k = 0; k < 64; k += 4) {
        float4 xv = *(const float4*)(xr + k);
        a0 += xv.x * W_e1[(k    ) * 256 + j];
        a1 += xv.y * W_e1[(k + 1) * 256 + j];
        a2 += xv.z * W_e1[(k + 2) * 256 + j];
        a3 += xv.w * W_e1[(k + 3) * 256 + j];
      }
      v += ((a0 + a1) + (a2 + a3));
    }
    linF[idx] = v;
  }

  gridbar_full(baru, NB);   // L2 flush of init data; flags all zero after this

  // ================= GRU role (blocks 0..31), DG for own batch ============
  if (bid < 32) {
    float* whh = S; float* w2 = S + 6240;
    float* sH = S + 12480; float* sLin = S + 20800;
    float* red = S + 29120;                       // [4][1536] ends 35264
    float* dgred = S + 35264;                     // [32][32]  ends 36288
    const int jb = bid * 8;
    for (int i = tid; i < 6144; i += NTHR) {
      int gg = i >> 11, r = i & 2047, jj = r >> 8, k = r & 255;
      whh[(gg * 8 + jj) * 260 + k] = W_hh[k * 768 + gg * 256 + jb + jj];
      w2 [(gg * 8 + jj) * 260 + k] = W2g [k * 768 + gg * 256 + jb + jj];
    }
    if (tid < 24) { int gg = tid / 8, jj = tid % 8;
      sb1[tid] = b_hh[gg * 256 + jb + jj];
      sb2[tid] = B2g [gg * 256 + jb + jj];
    }
    if (tid < 32) { len_s[tid] = lengths[tid];
                    decT[tid] = powf(0.99f, (float)(tid + 1)); }
    __syncthreads();

    for (int s = 0; s < kSteps; ++s) {
      const bool enc = (s < kT);
      // prefetch own-batch x for DG (static input, ungated)
      float xpre = 0.f;
      if (enc && tid < 64) xpre = x[(bid * kT + s) * kI + tid];

      const int tF1 = (s >= kT + 4) ? (s - 2) : 0;
      poll(FL, tid, s, tF1, 0);

      const float* hR = hBuf + (s & 3) * 8192;
      const float* lR = linF + s * 8192;
      float4 th[8], tl[8];
      #pragma unroll
      for (int u8 = 0; u8 < 8; ++u8) {
        int i4 = (tid + u8 * 256) * 4;
        th[u8] = cload4(hR + i4);
        tl[u8] = cload4(lR + i4);
      }
      waitvm();
      #pragma unroll
      for (int u8 = 0; u8 < 8; ++u8) {
        int idx = tid + u8 * 256; int b = idx >> 6, k4 = idx & 63;
        *(float4*)&sH[b * 260 + k4 * 4] = th[u8];
        float4 v;
        v.x = elu1(tl[u8].x); v.y = elu1(tl[u8].y);
        v.z = elu1(tl[u8].z); v.w = elu1(tl[u8].w);
        *(float4*)&sLin[b * 260 + k4 * 4] = v;
      }
      if (enc && tid < 64) sXb[tid] = xpre;
      __syncthreads();

      const float4* sH4 = (const float4*)sH;
      const float4* sL4 = (const float4*)sLin;
      const float4* wh4 = (const float4*)whh;
      const float4* w24 = (const float4*)w2;
      const int c  = tid & 7;
      const int b4 = (tid >> 3) & 7;
      const int kq = tid >> 6;
      float acc[24];
      #pragma unroll
      for (int a = 0; a < 24; ++a) acc[a] = 0.f;
      for (int kk = 0; kk < 16; ++kk) {
        int k4 = kq * 16 + kk;
        float4 wr[6];
        #pragma unroll
        for (int gg = 0; gg < 3; ++gg) {
          wr[gg]     = wh4[(gg * 8 + c) * 65 + k4];
          wr[3 + gg] = w24[(gg * 8 + c) * 65 + k4];
        }
        #pragma unroll
        for (int bi = 0; bi < 4; ++bi) {
          int b = bi * 8 + b4;
          float4 h4 = sH4[b * 65 + k4];
          float4 l4 = sL4[b * 65 + k4];
          #pragma unroll
          for (int gg = 0; gg < 3; ++gg) {
            float4 w = wr[gg];
            acc[bi * 6 + gg]     += h4.x * w.x + h4.y * w.y + h4.z * w.z + h4.w * w.w;
            w = wr[3 + gg];
            acc[bi * 6 + 3 + gg] += l4.x * w.x + l4.y * w.y + l4.z * w.z + l4.w * w.w;
          }
        }
      }
      #pragma unroll
      for (int bi = 0; bi < 4; ++bi)
        #pragma unroll
        for (int rr = 0; rr < 6; ++rr)
          red[kq * 1536 + rr * 256 + (bi * 8 + b4) * 8 + c] = acc[bi * 6 + rr];
      __syncthreads();
      {
        int b = tid >> 3, cc = tid & 7, jg = jb + cc;
        int lo = b * 8 + cc;
        float dots[6];
        #pragma unroll
        for (int rr = 0; rr < 6; ++rr)
          dots[rr] = (red[rr * 256 + lo] + red[1536 + rr * 256 + lo]) +
                     (red[3072 + rr * 256 + lo] + red[4608 + rr * 256 + lo]);
        float ghr = dots[0] + sb1[cc];
        float ghz = dots[1] + sb1[8 + cc];
        float ghn = dots[2] + sb1[16 + cc];
        float gir = dots[3] + sb2[cc];
        float giz = dots[4] + sb2[8 + cc];
        float gin = dots[5] + sb2[16 + cc];
        float r = 1.f / (1.f + expf(-(gir + ghr)));
        float z = 1.f / (1.f + expf(-(giz + ghz)));
        float n = tanhf(gin + r * ghn);
        float hold = sH[b * 260 + jg];
        float nh = (1.f - z) * n + z * hold;
        float hv = enc ? ((s < len_s[b]) ? nh : hold) : nh;
        cstore(&hBuf[((s + 1) & 3) * 8192 + b * 256 + jg], hv);
      }

      // ---- DG for own batch (encode only), then single publish ----
      if (enc) {
        // dg1: cell = [x(64), h(s)[bid](256)] @ W_dg1 (320x32)
        const int j4 = tid & 7, ks = tid >> 3;    // 8 j-quads x 32 k-slices(10)
        float4 pacc = make_float4(0.f, 0.f, 0.f, 0.f);
        const float* wd = W_dg1 + j4 * 4;
        #pragma unroll
        for (int kk = 0; kk < 10; ++kk) {
          int k = ks * 10 + kk;
          float cv = (k < 64) ? sXb[k] : sH[bid * 260 + (k - 64)];
          float4 w = *(const float4*)(wd + k * 32);
          pacc.x += cv * w.x; pacc.y += cv * w.y;
          pacc.z += cv * w.z; pacc.w += cv * w.w;
        }
        dgred[(j4 * 4 + 0) * 32 + ks] = pacc.x;
        dgred[(j4 * 4 + 1) * 32 + ks] = pacc.y;
        dgred[(j4 * 4 + 2) * 32 + ks] = pacc.z;
        dgred[(j4 * 4 + 3) * 32 + ks] = pacc.w;
        __syncthreads();
        if (tid < 32) {
          float a = b_dg1[tid];
          #pragma unroll 8
          for (int i = 0; i < 32; ++i) a += dgred[tid * 32 + i];
          l1s[tid] = elu1(a);
        }
        __syncthreads();
        if (tid < 32) {
          float sv = b_dg2[tid];
          #pragma unroll 8
          for (int k = 0; k < 32; ++k) sv += l1s[k] * W_dg2[k * 32 + tid];
          lgL[tid] = sv + g[(s * 32 + bid) * 32 + tid];
        }
        __syncthreads();
        if (tid == 0) {
          float best = lgL[0]; int d = 0;
          for (int j = 1; j < kD; ++j) {
            float v = lgL[j];
            if (v > best) { best = v; d = j; }
          }
          int cc2 = s + 1 + d, e = -1;
          if (cc2 < kT) e = cc2;
          else { int rr = cc2 - kT - 1;
                 if (rr >= 0 && !(rr & 1)) {
                   int kk2 = rr >> 1; if (kk2 < kOut) e = kT + kk2; } }
          selE = e; selD = d;
        }
        __syncthreads();
        if (tid < 64) {
          int e = selE;
          if (e >= 0) {
            float dec = decT[selD];
            float* rowp = linF + e * 8192 + bid * 256 + tid * 4;
            const float* pr = Pg + s * 8192 + bid * 256 + tid * 4;
            float4 v = cload4(rowp);
            float4 p = *(const float4*)pr;
            waitvm();
            v.x += dec * p.x; v.y += dec * p.y;
            v.z += dec * p.z; v.w += dec * p.w;
            cstore4(rowp, v);
          }
        }
      }
      setflag(FL, tid, bid, s + 1);
    }
  }
  // ================= F1 role (blocks 32..47) =================
  else if (bid < 48) {
    float* wf1 = S;
    const int jb = (bid - 32) * 16;
    for (int i = tid; i < 4096; i += NTHR) {
      int jj = i >> 8, k = i & 255;
      wf1[jj * 260 + k] = W_f1[k * 256 + jb + jj];
    }
    if (tid < 16) sb1[tid] = b_f1[jb + tid];
    __syncthreads();

    float* sHf = S + 4160; float* red = S + 12480; // [8][512]
    for (int s = kT + 1; s <= kSteps; ++s) {
      int tF2 = (s >= kT + 5) ? (s - 2) : 0;
      poll(FL, tid, s, 0, tF2);

      const float* hR = hBuf + (s & 3) * 8192;
      float4 th[8];
      #pragma unroll
      for (int u8 = 0; u8 < 8; ++u8) th[u8] = cload4(hR + (tid + u8 * 256) * 4);
      waitvm();
      #pragma unroll
      for (int u8 = 0; u8 < 8; ++u8) {
        int idx = tid + u8 * 256; int b = idx >> 6, k4 = idx & 63;
        *(float4*)&sHf[b * 260 + k4 * 4] = th[u8];
      }
      __syncthreads();
      const float4* sH4 = (const float4*)sHf;
      const float4* w4p = (const float4*)wf1;
      const int cq = tid & 3, b4 = (tid >> 2) & 7, kq = tid >> 5;
      float acc[16];
      #pragma unroll
      for (int a = 0; a < 16; ++a) acc[a] = 0.f;
      for (int kk = 0; kk < 8; ++kk) {
        int k4 = kq * 8 + kk;
        float4 wr[4];
        #pragma unroll
        for (int ci = 0; ci < 4; ++ci) wr[ci] = w4p[(cq * 4 + ci) * 65 + k4];
        #pragma unroll
        for (int bi = 0; bi < 4; ++bi) {
          float4 h4 = sH4[(bi * 8 + b4) * 65 + k4];
          #pragma unroll
          for (int ci = 0; ci < 4; ++ci) {
            float4 w = wr[ci];
            acc[bi * 4 + ci] += h4.x * w.x + h4.y * w.y + h4.z * w.z + h4.w * w.w;
          }
        }
      }
      #pragma unroll
      for (int bi = 0; bi < 4; ++bi)
        #pragma unroll
        for (int ci = 0; ci < 4; ++ci)
          red[kq * 512 + (bi * 4 + ci) * 32 + cq * 8 + b4] = acc[bi * 4 + ci];
      __syncthreads();
      #pragma unroll
      for (int u2 = 0; u2 < 2; ++u2) {
        int o = tid * 2 + u2; int b = o >> 4, col = o & 15;
        int gg = ((b >> 3) * 4 + (col & 3)) * 32 + (col >> 2) * 8 + (b & 7);
        float v = 0.f;
        #pragma unroll
        for (int kq2 = 0; kq2 < 8; ++kq2) v += red[kq2 * 512 + gg];
        v += sb1[col];
        cstore(&o1B[(s & 3) * 8192 + b * 256 + (bid - 32) * 16 + col],
               v > 0.f ? v : 0.f);
      }
      __syncthreads();
      setflag(FL, tid, bid, s + 1);
    }
  }
  // ================= F2 role (blocks 48..55) =================
  else {
    float* wf2 = S;
    const int cb = (bid - 48) * 8;
    for (int i = tid; i < 2048; i += NTHR) {
      int cc = i >> 8, k = i & 255;
      wf2[cc * 260 + k] = W_f2[k * 64 + cb + cc];
    }
    if (tid < 8) sb2[tid] = b_f2[cb + tid];
    __syncthreads();

    float* sO = S + 2080; float* red = S + 10400;  // [4][256]
    for (int s = kT + 2; s <= kSteps + 1; ++s) {
      poll(FL, tid, 0, s, 0);

      const float* oR = o1B + ((s - 1) & 3) * 8192;
      float4 to[8];
      #pragma unroll
      for (int u8 = 0; u8 < 8; ++u8) to[u8] = cload4(oR + (tid + u8 * 256) * 4);
      waitvm();
      #pragma unroll
      for (int u8 = 0; u8 < 8; ++u8) {
        int idx = tid + u8 * 256; int b = idx >> 6, k4 = idx & 63;
        *(float4*)&sO[b * 260 + k4 * 4] = to[u8];
      }
      __syncthreads();
      const float4* sO4 = (const float4*)sO;
      const float4* w4p = (const float4*)wf2;
      const int c = tid & 7, b4 = (tid >> 3) & 7, kq = tid >> 6;
      float acc[4] = {0.f, 0.f, 0.f, 0.f};
      for (int kk = 0; kk < 16; ++kk) {
        int k4 = kq * 16 + kk;
        float4 w = w4p[c * 65 + k4];
        #pragma unroll
        for (int bi = 0; bi < 4; ++bi) {
          float4 o4 = sO4[(bi * 8 + b4) * 65 + k4];
          acc[bi] += o4.x * w.x + o4.y * w.y + o4.z * w.z + o4.w * w.w;
        }
      }
      #pragma unroll
      for (int bi = 0; bi < 4; ++bi)
        red[kq * 256 + bi * 64 + b4 * 8 + c] = acc[bi];
      __syncthreads();
      { int b = tid >> 3, col = tid & 7;
        int gg = (b >> 3) * 64 + (b & 7) * 8 + col;
        float v = (red[gg] + red[256 + gg]) + (red[512 + gg] + red[768 + gg]);
        out[(b * kOut + (s - 2 - kT)) * kC + (bid - 48) * 8 + col] =
            v + sb2[col];
      }
      __syncthreads();
      setflag(FL, tid, bid, s + 1);
    }
  }
}

extern "C" void kernel_launch(void* const* d_in, const int* in_sizes, int n_in,
                              void* d_out, int out_size, void* d_ws, size_t ws_size,
                              hipStream_t stream) {
  (void)in_sizes; (void)n_in; (void)out_size; (void)ws_size;
  const float* x      = (const float*)d_in[0];
  const int*   lens   = (const int*)  d_in[1];
  const float* W_dg1  = (const float*)d_in[3];
  const float* b_dg1  = (const float*)d_in[4];
  const float* W_dg2  = (const float*)d_in[5];
  const float* b_dg2  = (const float*)d_in[6];
  const float* W_e1   = (const float*)d_in[7];
  const float* b_e1   = (const float*)d_in[8];
  const float* W_e2   = (const float*)d_in[9];
  const float* b_e2   = (const float*)d_in[10];
  const float* W_ih   = (const float*)d_in[11];
  const float* b_ih   = (const float*)d_in[12];
  const float* W_hh   = (const float*)d_in[13];
  const float* b_hh   = (const float*)d_in[14];
  const float* W_f1   = (const float*)d_in[15];
  const float* b_f1   = (const float*)d_in[16];
  const float* W_f2   = (const float*)d_in[17];
  const float* b_f2   = (const float*)d_in[18];

  hipMemsetAsync(d_ws, 0, WS_ZERO_BYTES, stream);
  delay_rnn<<<dim3(NB), dim3(NTHR), 0, stream>>>(
      x, lens, W_dg1, b_dg1, W_dg2, b_dg2, W_e1, b_e1, W_e2, b_e2,
      W_ih, b_ih, W_hh, b_hh, W_f1, b_f1, W_f2, b_f2,
      (float*)d_out, (float*)d_ws);
}

// Round 8
// 2192.482 us; speedup vs baseline: 1.6940x; 1.0916x over previous
//
#include <hip/hip_runtime.h>
#include <math.h>

// ---------------------------------------------------------------------------
// DelayRNN persistent kernel, R18: R11 pipeline minus E1, coalesced publishes.
// R17 post-mortem: per-block serial DG tail (+3us/enc-step, 4.7x bank
// conflicts) -> regression; R12-R17 establish R11's 4-role pipeline as the
// best structure (DG/E1 latencies hidden; floor = GRU h-cycle). R18:
//  * E1 role DELETED with ZERO pacing change: lin(e) = linF[e] (init:
//    x_e@W_e1[0:64]+b_e1) + events decay[d]*P[s'] (d>=1, by DG, same flag
//    FL_DG that R11's GRU already polls at >= s); d=0 correction stays
//    consumption-time via selG/P (R11 verbatim). 89 -> 57 blocks.
//  * h/o1/event stores coalesced: LDS stage + global_store_dwordx4 sc0 sc1
//    (ext_vector asm operand -- struct-float4 constraint was the R1 error).
// Blocks: 32 GRU | 1 DG | 16 F1 | 8 F2 = 57.
// Flags: FL[b]=GRU-h (b<32) | 32=DG (sel+events) | 33..48 F1 | 49..56 F2.
// Pacing (== R11 with E1 edge removed):
//   GRU_s : FL_H>=s, FL_DG>=(s>=1?min(s,128):0), FL_F1>=s-2 [s>=132]
//   DG_s  : FL_H>=s                          (s in 0..127)
//   F1_s  : FL_H>=s, FL_F2>=s-2 [s>=133]     (s in 129..160)
//   F2_s  : FL_F1>=s                          (s in 130..161)
// ---------------------------------------------------------------------------

#define kB 32
#define kT 128
#define kI 64
#define kH 256
#define kD 32
#define kC 64
#define kOut 32
#define kSteps (kT + kOut)            // 160
#define NB 57
#define NTHR 256
#define NT_ALL (NB * NTHR)

// ws float offsets. Zeroed region: [0, WS_NZ)
#define WS_FL    384                   // int flags FL[57] @ stride 16 ints
#define WS_H     1856                  // h[4][32][256]
#define WS_SEL   (WS_H + 4*8192)       // sel[4][32] (int)
#define WS_NZ    (WS_SEL + 128)        // end of zero region
#define WS_W2    WS_NZ                 // W2 = W_e2@W_ih [256][768]
#define WS_B2    (WS_W2 + kH*3*kH)     // B2 [768]
#define WS_G     (WS_B2 + 3*kH)        // gumbel [T*B*D]
#define WS_P     (WS_G + kT*kB*kD)     // P[s][b][j] = x_s @ W_e1[64:128]
#define WS_LINF  (WS_P + kT*kB*kH)     // linF[e][b][j] = x_e@W_e1[0:64]+b_e1 (+events)
#define WS_O1    (WS_LINF + kSteps*kB*kH) // o1[4][32][256]
#define WS_ZERO_BYTES ((size_t)WS_NZ * sizeof(float))

typedef float f32x4v __attribute__((ext_vector_type(4)));

// ---- coherent access (agent scope, L3 coherence point) ----
__device__ __forceinline__ float cload(const float* p) {
  return __hip_atomic_load(p, __ATOMIC_RELAXED, __HIP_MEMORY_SCOPE_AGENT);
}
__device__ __forceinline__ void cstore(float* p, float v) {
  __hip_atomic_store(p, v, __ATOMIC_RELAXED, __HIP_MEMORY_SCOPE_AGENT);
}
__device__ __forceinline__ int cload_i(const int* p) {
  return __hip_atomic_load(p, __ATOMIC_RELAXED, __HIP_MEMORY_SCOPE_AGENT);
}
__device__ __forceinline__ void cstore_i(int* p, int v) {
  __hip_atomic_store(p, v, __ATOMIC_RELAXED, __HIP_MEMORY_SCOPE_AGENT);
}
__device__ __forceinline__ float4 cload4(const float* p) {
  float4 r;
  asm volatile("global_load_dwordx4 %0, %1, off sc0 sc1" : "=v"(r) : "v"(p));
  return r;
}
// 16B coherent store: ext_vector operand (struct float4 as asm input is the
// unsupported "indirect register input"; ext_vector maps to a VGPR quad).
__device__ __forceinline__ void cstore4w(float* p, float4 v) {
  f32x4v t; t.x = v.x; t.y = v.y; t.z = v.z; t.w = v.w;
  asm volatile("global_store_dwordx4 %0, %1, off sc0 sc1" :: "v"(p), "v"(t) : "memory");
}
__device__ __forceinline__ void waitvm() {
  asm volatile("s_waitcnt vmcnt(0)" ::: "memory");
}

// ---- flag sync ----
// FL[i]: i<32 GRU-h | 32=DG | 33..48 F1 | 49..56 F2.
__device__ __forceinline__ void poll(const int* FL, int tid,
                                     int tH, int tDG, int tF1, int tF2) {
  int thr;
  if      (tid < 32) thr = tH;
  else if (tid == 32) thr = tDG;
  else if (tid < 49) thr = tF1;
  else if (tid < 57) thr = tF2;
  else thr = 0;
  const int* p = FL + tid * 16;
  for (;;) {
    int ok = (thr <= 0) || (cload_i(p) >= thr);
    if (__syncthreads_count(ok) == NTHR) return;
    __builtin_amdgcn_s_sleep(2);
  }
}
// Publish: all data stores drained per-wave, then block-sync, then flag store.
__device__ __forceinline__ void setflag(int* FL, int tid, int idx, int val) {
  waitvm();
  __syncthreads();
  if (tid == 0) cstore_i(FL + idx * 16, val);
}

// ---- Threefry-2x32 (jax partitionable path) ----
__device__ __forceinline__ void tf2x32(unsigned k0, unsigned k1,
                                       unsigned x0, unsigned x1,
                                       unsigned& o0, unsigned& o1) {
  unsigned ks2 = k0 ^ k1 ^ 0x1BD11BDAu;
  unsigned v0 = x0 + k0, v1 = x1 + k1;
#define TFR(r) { v0 += v1; v1 = (v1 << (r)) | (v1 >> (32-(r))); v1 ^= v0; }
  TFR(13) TFR(15) TFR(26) TFR(6)   v0 += k1;  v1 += ks2 + 1u;
  TFR(17) TFR(29) TFR(16) TFR(24)  v0 += ks2; v1 += k0  + 2u;
  TFR(13) TFR(15) TFR(26) TFR(6)   v0 += k0;  v1 += k1  + 3u;
  TFR(17) TFR(29) TFR(16) TFR(24)  v0 += k1;  v1 += ks2 + 4u;
  TFR(13) TFR(15) TFR(26) TFR(6)   v0 += ks2; v1 += k0  + 5u;
#undef TFR
  o0 = v0; o1 = v1;
}
__device__ __forceinline__ float bits_to_gumbel(unsigned bits) {
  float f = __uint_as_float((bits >> 9) | 0x3F800000u) - 1.0f;
  float u = f + 1.17549435e-38f;
  return -logf(-logf(u));
}

__device__ __forceinline__ void gridbar_full(unsigned* u, unsigned target) {
  __syncthreads();
  if (threadIdx.x == 0) {
    __threadfence();
    __hip_atomic_fetch_add(&u[320], 1u, __ATOMIC_ACQ_REL, __HIP_MEMORY_SCOPE_AGENT);
    while (__hip_atomic_load(&u[320], __ATOMIC_RELAXED, __HIP_MEMORY_SCOPE_AGENT) < target)
      __builtin_amdgcn_s_sleep(1);
    __threadfence();
  }
  __syncthreads();
}

__device__ __forceinline__ float elu1(float v) { return v > 0.f ? v : expm1f(v); }

__global__ __launch_bounds__(NTHR)
void delay_rnn(const float* __restrict__ x, const int* __restrict__ lengths,
               const float* __restrict__ W_dg1, const float* __restrict__ b_dg1,
               const float* __restrict__ W_dg2, const float* __restrict__ b_dg2,
               const float* __restrict__ W_e1,  const float* __restrict__ b_e1,
               const float* __restrict__ W_e2,  const float* __restrict__ b_e2,
               const float* __restrict__ W_ih,  const float* __restrict__ b_ih,
               const float* __restrict__ W_hh,  const float* __restrict__ b_hh,
               const float* __restrict__ W_f1,  const float* __restrict__ b_f1,
               const float* __restrict__ W_f2,  const float* __restrict__ b_f2,
               float* __restrict__ out, float* __restrict__ ws) {
  const int tid = threadIdx.x;
  const int bid = blockIdx.x;
  const int gid = bid * NTHR + tid;

  unsigned* baru = (unsigned*)ws;
  int*   FL    = (int*)(ws + WS_FL);
  float* hBuf  = ws + WS_H;
  int*   selG  = (int*)(ws + WS_SEL);
  float* W2g   = ws + WS_W2;
  float* B2g   = ws + WS_B2;
  float* g     = ws + WS_G;
  float* Pg    = ws + WS_P;
  float* linF  = ws + WS_LINF;
  float* o1B   = ws + WS_O1;

  __shared__ float S[35520];           // role-carved (max: GRU + hstage)
  __shared__ float sb1[32], sb2[32], dec_sh[32];
  __shared__ int   sel[32], len_s[32], edest[32];

  // ---------------- init: gumbel, W2 = W_e2@W_ih, B2, P, linF ----------
  {
    unsigned k0, k1;
    tf2x32(0u, 42u, 0u, 0u, k0, k1);
    for (int i = gid; i < kT * kB * kD; i += NT_ALL) {
      unsigned a, b;
      tf2x32(k0, k1, 0u, (unsigned)i, a, b);
      g[i] = bits_to_gumbel(a ^ b);
    }
  }
  for (int idx = gid; idx < kH * 3 * kH; idx += NT_ALL) {
    int k = idx / (3 * kH), n = idx % (3 * kH);
    const float* wr = W_e2 + k * kH;
    float s0 = 0, s1 = 0, s2 = 0, s3 = 0;
    for (int m = 0; m < kH; m += 4) {
      float4 wv = *(const float4*)(wr + m);
      s0 += wv.x * W_ih[(m    ) * 3 * kH + n];
      s1 += wv.y * W_ih[(m + 1) * 3 * kH + n];
      s2 += wv.z * W_ih[(m + 2) * 3 * kH + n];
      s3 += wv.w * W_ih[(m + 3) * 3 * kH + n];
    }
    W2g[idx] = ((s0 + s1) + (s2 + s3));
  }
  for (int n = gid; n < 3 * kH; n += NT_ALL) {
    float s = b_ih[n];
    for (int m = 0; m < kH; ++m) s += b_e2[m] * W_ih[m * 3 * kH + n];
    B2g[n] = s;
  }
  // P[s][b][j] = sum_k x[b,s,k] * W_e1[64+k][j]  (mem-part weights)
  for (int idx = gid; idx < kT * kB * kH; idx += NT_ALL) {
    int s = idx >> 13, r = idx & 8191, b = r >> 8, j = r & 255;
    const float* xr = x + (b * kT + s) * kI;
    float a0 = 0, a1 = 0, a2 = 0, a3 = 0;
    for (int k = 0; k < 64; k += 4) {
      float4 xv = *(const float4*)(xr + k);
      a0 += xv.x * W_e1[(64 + k) * 256 + j];
      a1 += xv.y * W_e1[(65 + k) * 256 + j];
      a2 += xv.z * W_e1[(66 + k) * 256 + j];
      a3 += xv.w * W_e1[(67 + k) * 256 + j];
    }
    Pg[idx] = ((a0 + a1) + (a2 + a3));
  }
  // linF[e][b][j] = b_e1[j] + (e<kT ? x_e @ W_e1[0:64] : 0)
  for (int idx = gid; idx < kSteps * kB * kH; idx += NT_ALL) {
    int e = idx >> 13, r = idx & 8191, b = r >> 8, j = r & 255;
    float v = b_e1[j];
    if (e < kT) {
      const float* xr = x + (b * kT + e) * kI;
      float a0 = 0, a1 = 0, a2 = 0, a3 = 0;
      for (int k = 0; k < 64; k += 4) {
        float4 xv = *(const float4*)(xr + k);
        a0 += xv.x * W_e1[(k    ) * 256 + j];
        a1 += xv.y * W_e1[(k + 1) * 256 + j];
        a2 += xv.z * W_e1[(k + 2) * 256 + j];
        a3 += xv.w * W_e1[(k + 3) * 256 + j];
      }
      v += ((a0 + a1) + (a2 + a3));
    }
    linF[idx] = v;
  }

  gridbar_full(baru, NB);   // L2 flush of init data; flags all zero after this

  // ================= GRU role (blocks 0..31) =================
  if (bid < 32) {
    float* whh = S; float* w2 = S + 6240;
    const int jb = bid * 8;
    for (int i = tid; i < 6144; i += NTHR) {
      int gg = i >> 11, r = i & 2047, jj = r >> 8, k = r & 255;
      whh[(gg * 8 + jj) * 260 + k] = W_hh[k * 768 + gg * 256 + jb + jj];
      w2 [(gg * 8 + jj) * 260 + k] = W2g [k * 768 + gg * 256 + jb + jj];
    }
    if (tid < 24) { int gg = tid / 8, jj = tid % 8;
      sb1[tid] = b_hh[gg * 256 + jb + jj];
      sb2[tid] = B2g [gg * 256 + jb + jj];
    }
    if (tid < 32) len_s[tid] = lengths[tid];
    __syncthreads();

    float* sH = S + 12480; float* sLin = S + 20800;
    float* red = S + 29120;                       // [4][1536] ends 35264
    float* hstage = S + 35264;                    // [32][8]   ends 35520
    for (int s = 0; s < kSteps; ++s) {
      int tDG = (s >= 1) ? (s < kT ? s : kT) : 0;
      int tF1 = (s >= kT + 4) ? (s - 2) : 0;
      poll(FL, tid, s, tDG, tF1, 0);

      const float* hR = hBuf + (s & 3) * 8192;
      const float* lR = linF + s * 8192;
      const bool useC = (s >= 1 && s < kT);
      const float4* P4 = (const float4*)(Pg + (s - 1) * 8192);
      const int* selR = selG + ((s - 1) & 3) * 32;
      float4 th[8], tl[8], tp[8];
      int tsel[8];
      #pragma unroll
      for (int u8 = 0; u8 < 8; ++u8) {
        int i4 = (tid + u8 * 256) * 4;
        th[u8] = cload4(hR + i4);
        tl[u8] = cload4(lR + i4);
      }
      if (useC) {
        #pragma unroll
        for (int u8 = 0; u8 < 8; ++u8) {
          int idx = tid + u8 * 256; int b = idx >> 6, k4 = idx & 63;
          tp[u8] = P4[b * 64 + k4];
          tsel[u8] = cload_i(&selR[b]);
        }
      }
      waitvm();
      #pragma unroll
      for (int u8 = 0; u8 < 8; ++u8) {
        int idx = tid + u8 * 256; int b = idx >> 6, k4 = idx & 63;
        *(float4*)&sH[b * 260 + k4 * 4] = th[u8];
        float cx = 0.f, cy = 0.f, cz = 0.f, cw = 0.f;
        if (useC && tsel[u8] == 0) {
          cx = 0.99f * tp[u8].x; cy = 0.99f * tp[u8].y;
          cz = 0.99f * tp[u8].z; cw = 0.99f * tp[u8].w;
        }
        float4 v;
        v.x = elu1(tl[u8].x + cx);
        v.y = elu1(tl[u8].y + cy);
        v.z = elu1(tl[u8].z + cz);
        v.w = elu1(tl[u8].w + cw);
        *(float4*)&sLin[b * 260 + k4 * 4] = v;
      }
      __syncthreads();
      const float4* sH4 = (const float4*)sH;
      const float4* sL4 = (const float4*)sLin;
      const float4* wh4 = (const float4*)whh;
      const float4* w24 = (const float4*)w2;
      const int c  = tid & 7;
      const int b4 = (tid >> 3) & 7;
      const int kq = tid >> 6;
      float acc[24];
      #pragma unroll
      for (int a = 0; a < 24; ++a) acc[a] = 0.f;
      for (int kk = 0; kk < 16; ++kk) {
        int k4 = kq * 16 + kk;
        float4 wr[6];
        #pragma unroll
        for (int gg = 0; gg < 3; ++gg) {
          wr[gg]     = wh4[(gg * 8 + c) * 65 + k4];
          wr[3 + gg] = w24[(gg * 8 + c) * 65 + k4];
        }
        #pragma unroll
        for (int bi = 0; bi < 4; ++bi) {
          int b = bi * 8 + b4;
          float4 h4 = sH4[b * 65 + k4];
          float4 l4 = sL4[b * 65 + k4];
          #pragma unroll
          for (int gg = 0; gg < 3; ++gg) {
            float4 w = wr[gg];
            acc[bi * 6 + gg]     += h4.x * w.x + h4.y * w.y + h4.z * w.z + h4.w * w.w;
            w = wr[3 + gg];
            acc[bi * 6 + 3 + gg] += l4.x * w.x + l4.y * w.y + l4.z * w.z + l4.w * w.w;
          }
        }
      }
      #pragma unroll
      for (int bi = 0; bi < 4; ++bi)
        #pragma unroll
        for (int rr = 0; rr < 6; ++rr)
          red[kq * 1536 + rr * 256 + (bi * 8 + b4) * 8 + c] = acc[bi * 6 + rr];
      __syncthreads();
      {
        int b = tid >> 3, cc = tid & 7, jg = jb + cc;
        int lo = b * 8 + cc;
        float dots[6];
        #pragma unroll
        for (int rr = 0; rr < 6; ++rr)
          dots[rr] = (red[rr * 256 + lo] + red[1536 + rr * 256 + lo]) +
                     (red[3072 + rr * 256 + lo] + red[4608 + rr * 256 + lo]);
        float ghr = dots[0] + sb1[cc];
        float ghz = dots[1] + sb1[8 + cc];
        float ghn = dots[2] + sb1[16 + cc];
        float gir = dots[3] + sb2[cc];
        float giz = dots[4] + sb2[8 + cc];
        float gin = dots[5] + sb2[16 + cc];
        float r = 1.f / (1.f + expf(-(gir + ghr)));
        float z = 1.f / (1.f + expf(-(giz + ghz)));
        float n = tanhf(gin + r * ghn);
        float hold = sH[b * 260 + jg];
        float nh = (1.f - z) * n + z * hold;
        float hv = (s < kT) ? ((s < len_s[b]) ? nh : hold) : nh;
        hstage[b * 8 + cc] = hv;
      }
      __syncthreads();
      if (tid < 64) {                        // coalesced h publish (2 q/b)
        int b = tid >> 1, q = tid & 1;
        float4 h4 = *(const float4*)&hstage[b * 8 + q * 4];
        cstore4w(&hBuf[((s + 1) & 3) * 8192 + b * 256 + jb + q * 4], h4);
      }
      setflag(FL, tid, bid, s + 1);
    }
  }
  // ================= DG role (block 32) =================
  else if (bid == 32) {
    float* wdg1 = S; float* wdg2 = S + 10368;
    for (int i = tid; i < 10240; i += NTHR) {
      int j = i / 320, k = i % 320;
      wdg1[j * 324 + k] = W_dg1[k * 32 + j];
    }
    for (int i = tid; i < 1024; i += NTHR) wdg2[i] = W_dg2[i];
    if (tid < 32) { sb1[tid] = b_dg1[tid]; sb2[tid] = b_dg2[tid];
                    dec_sh[tid] = powf(0.99f, (float)(tid + 1)); }
    __syncthreads();

    float* sXH = S + 11392;                       // [32][324]
    float* red = S + 21760;                       // [4][1024]
    float* l1s = S + 25856;                       // [32][36]
    float* lg  = S + 27008;                       // [32][33]
    for (int s = 0; s < kT; ++s) {
      // prefetch x (static input, ungated)
      float4 tx[2];
      #pragma unroll
      for (int u2 = 0; u2 < 2; ++u2) {
        int idx = tid + u2 * 256; int b = idx >> 4, k4 = idx & 15;
        tx[u2] = *(const float4*)(x + (b * kT + s) * kI + k4 * 4);
      }
      poll(FL, tid, s, 0, 0, 0);

      const float* hR = hBuf + (s & 3) * 8192;
      float4 th[8];
      #pragma unroll
      for (int u8 = 0; u8 < 8; ++u8) th[u8] = cload4(hR + (tid + u8 * 256) * 4);
      waitvm();
      #pragma unroll
      for (int u8 = 0; u8 < 8; ++u8) {
        int idx = tid + u8 * 256; int b = idx >> 6, k4 = idx & 63;
        *(float4*)&sXH[b * 324 + 64 + k4 * 4] = th[u8];
      }
      #pragma unroll
      for (int u2 = 0; u2 < 2; ++u2) {
        int idx = tid + u2 * 256; int b = idx >> 4, k4 = idx & 15;
        *(float4*)&sXH[b * 324 + k4 * 4] = tx[u2];
      }
      __syncthreads();
      {
        const float4* sA4 = (const float4*)sXH;
        const float4* wd4 = (const float4*)wdg1;
        const int cq = tid & 7, b4 = (tid >> 3) & 7, kq = tid >> 6;
        float acc[16];
        #pragma unroll
        for (int a = 0; a < 16; ++a) acc[a] = 0.f;
        for (int kk = 0; kk < 20; ++kk) {
          int k4 = kq * 20 + kk;
          float4 wr[4];
          #pragma unroll
          for (int ci = 0; ci < 4; ++ci) wr[ci] = wd4[(cq * 4 + ci) * 81 + k4];
          #pragma unroll
          for (int bi = 0; bi < 4; ++bi) {
            float4 a4 = sA4[(bi * 8 + b4) * 81 + k4];
            #pragma unroll
            for (int ci = 0; ci < 4; ++ci) {
              float4 w = wr[ci];
              acc[bi * 4 + ci] += a4.x * w.x + a4.y * w.y + a4.z * w.z + a4.w * w.w;
            }
          }
        }
        #pragma unroll
        for (int bi = 0; bi < 4; ++bi)
          #pragma unroll
          for (int ci = 0; ci < 4; ++ci)
            red[kq * 1024 + (ci * 4 + bi) * 64 + cq * 8 + b4] = acc[bi * 4 + ci];
        __syncthreads();
        #pragma unroll
        for (int u4 = 0; u4 < 4; ++u4) {
          int o = tid * 4 + u4; int b = o >> 5, col = o & 31;
          int ci = col & 3, cq2 = col >> 2, bi = b >> 3, b42 = b & 7;
          int f = (ci * 4 + bi) * 64 + cq2 * 8 + b42;
          float v = (red[f] + red[1024 + f]) + (red[2048 + f] + red[3072 + f]);
          l1s[b * 36 + col] = elu1(v + sb1[col]);
        }
      }
      __syncthreads();
      for (int it = 0; it < 4; ++it) {            // dg2 + gumbel
        int i = tid + it * 256; int b = i >> 5, j = i & 31;
        float sv = sb2[j];
        for (int k = 0; k < 32; ++k) sv += l1s[b * 36 + k] * wdg2[k * 32 + j];
        lg[b * 33 + j] = sv + g[(s * 32 + b) * 32 + j];
      }
      __syncthreads();
      if (tid < 32) {
        float best = lg[tid * 33]; int bi = 0;
        for (int j = 1; j < 32; ++j) {
          float v = lg[tid * 33 + j];
          if (v > best) { best = v; bi = j; }
        }
        sel[tid] = bi;
      }
      __syncthreads();
      if (tid < 32) {
        cstore_i(&selG[(s & 3) * 32 + tid], sel[tid]);
        int d = sel[tid], e = -1;
        if (d > 0) {
          int c = s + 1 + d;
          if (c < kT) e = c;
          else { int rr = c - kT - 1;
                 if (rr >= 0 && !(rr & 1)) {
                   int kk2 = rr >> 1; if (kk2 < kOut) e = kT + kk2; } }
        }
        edest[tid] = e;
      }
      __syncthreads();
      {
        // event AXPY (d >= 1): linF[e][b] += dec_sh[d] * P[s][b]
        float4 tv[8], tp2[8];
        int te[8], tb2[8];
        #pragma unroll
        for (int it = 0; it < 8; ++it) {
          int i = tid + it * 256; int b = i >> 6, q = i & 63;
          te[it] = edest[b]; tb2[it] = b;
          if (te[it] >= 0) {
            tv[it]  = cload4(linF + te[it] * 8192 + b * 256 + q * 4);
            tp2[it] = *(const float4*)(Pg + s * 8192 + b * 256 + q * 4);
          }
        }
        waitvm();
        #pragma unroll
        for (int it = 0; it < 8; ++it) {
          int i = tid + it * 256; int q = i & 63;
          if (te[it] >= 0) {
            float dec = dec_sh[sel[tb2[it]]];
            float4 v = tv[it], p = tp2[it];
            v.x += dec * p.x; v.y += dec * p.y;
            v.z += dec * p.z; v.w += dec * p.w;
            cstore4w(linF + te[it] * 8192 + tb2[it] * 256 + q * 4, v);
          }
        }
      }
      setflag(FL, tid, 32, s + 1);
    }
  }
  // ================= F1 role (blocks 33..48) =================
  else if (bid < 49) {
    float* wf1 = S;
    const int jb = (bid - 33) * 16;
    for (int i = tid; i < 4096; i += NTHR) {
      int jj = i >> 8, k = i & 255;
      wf1[jj * 260 + k] = W_f1[k * 256 + jb + jj];
    }
    if (tid < 16) sb1[tid] = b_f1[jb + tid];
    __syncthreads();

    float* sHf = S + 4160; float* red = S + 12480; // [8][512] ends 16576
    float* ostage = S + 16576;                     // [32][16] ends 17088
    for (int s = kT + 1; s <= kSteps; ++s) {
      int tF2 = (s >= kT + 5) ? (s - 2) : 0;
      poll(FL, tid, s, 0, 0, tF2);

      const float* hR = hBuf + (s & 3) * 8192;
      float4 th[8];
      #pragma unroll
      for (int u8 = 0; u8 < 8; ++u8) th[u8] = cload4(hR + (tid + u8 * 256) * 4);
      waitvm();
      #pragma unroll
      for (int u8 = 0; u8 < 8; ++u8) {
        int idx = tid + u8 * 256; int b = idx >> 6, k4 = idx & 63;
        *(float4*)&sHf[b * 260 + k4 * 4] = th[u8];
      }
      __syncthreads();
      const float4* sH4 = (const float4*)sHf;
      const float4* w4p = (const float4*)wf1;
      const int cq = tid & 3, b4 = (tid >> 2) & 7, kq = tid >> 5;
      float acc[16];
      #pragma unroll
      for (int a = 0; a < 16; ++a) acc[a] = 0.f;
      for (int kk = 0; kk < 8; ++kk) {
        int k4 = kq * 8 + kk;
        float4 wr[4];
        #pragma unroll
        for (int ci = 0; ci < 4; ++ci) wr[ci] = w4p[(cq * 4 + ci) * 65 + k4];
        #pragma unroll
        for (int bi = 0; bi < 4; ++bi) {
          float4 h4 = sH4[(bi * 8 + b4) * 65 + k4];
          #pragma unroll
          for (int ci = 0; ci < 4; ++ci) {
            float4 w = wr[ci];
            acc[bi * 4 + ci] += h4.x * w.x + h4.y * w.y + h4.z * w.z + h4.w * w.w;
          }
        }
      }
      #pragma unroll
      for (int bi = 0; bi < 4; ++bi)
        #pragma unroll
        for (int ci = 0; ci < 4; ++ci)
          red[kq * 512 + (bi * 4 + ci) * 32 + cq * 8 + b4] = acc[bi * 4 + ci];
      __syncthreads();
      #pragma unroll
      for (int u2 = 0; u2 < 2; ++u2) {
        int o = tid * 2 + u2; int b = o >> 4, col = o & 15;
        int gg = ((b >> 3) * 4 + (col & 3)) * 32 + (col >> 2) * 8 + (b & 7);
        float v = 0.f;
        #pragma unroll
        for (int kq2 = 0; kq2 < 8; ++kq2) v += red[kq2 * 512 + gg];
        v += sb1[col];
        ostage[b * 16 + col] = v > 0.f ? v : 0.f;
      }
      __syncthreads();
      if (tid < 128) {                       // coalesced o1 publish (4 q/b)
        int b = tid >> 2, q = tid & 3;
        float4 o4 = *(const float4*)&ostage[b * 16 + q * 4];
        cstore4w(&o1B[(s & 3) * 8192 + b * 256 + jb + q * 4], o4);
      }
      setflag(FL, tid, bid, s + 1);
    }
  }
  // ================= F2 role (blocks 49..56) =================
  else {
    float* wf2 = S;
    const int cb = (bid - 49) * 8;
    for (int i = tid; i < 2048; i += NTHR) {
      int cc = i >> 8, k = i & 255;
      wf2[cc * 260 + k] = W_f2[k * 64 + cb + cc];
    }
    if (tid < 8) sb2[tid] = b_f2[cb + tid];
    __syncthreads();

    float* sO = S + 2080; float* red = S + 10400;  // [4][256]
    for (int s = kT + 2; s <= kSteps + 1; ++s) {
      poll(FL, tid, 0, 0, s, 0);

      const float* oR = o1B + ((s - 1) & 3) * 8192;
      float4 to[8];
      #pragma unroll
      for (int u8 = 0; u8 < 8; ++u8) to[u8] = cload4(oR + (tid + u8 * 256) * 4);
      waitvm();
      #pragma unroll
      for (int u8 = 0; u8 < 8; ++u8) {
        int idx = tid + u8 * 256; int b = idx >> 6, k4 = idx & 63;
        *(float4*)&sO[b * 260 + k4 * 4] = to[u8];
      }
      __syncthreads();
      const float4* sO4 = (const float4*)sO;
      const float4* w4p = (const float4*)wf2;
      const int c = tid & 7, b4 = (tid >> 3) & 7, kq = tid >> 6;
      float acc[4] = {0.f, 0.f, 0.f, 0.f};
      for (int kk = 0; kk < 16; ++kk) {
        int k4 = kq * 16 + kk;
        float4 w = w4p[c * 65 + k4];
        #pragma unroll
        for (int bi = 0; bi < 4; ++bi) {
          float4 o4 = sO4[(bi * 8 + b4) * 65 + k4];
          acc[bi] += o4.x * w.x + o4.y * w.y + o4.z * w.z + o4.w * w.w;
        }
      }
      #pragma unroll
      for (int bi = 0; bi < 4; ++bi)
        red[kq * 256 + bi * 64 + b4 * 8 + c] = acc[bi];
      __syncthreads();
      { int b = tid >> 3, col = tid & 7;
        int gg = (b >> 3) * 64 + (b & 7) * 8 + col;
        float v = (red[gg] + red[256 + gg]) + (red[512 + gg] + red[768 + gg]);
        out[(b * kOut + (s - 2 - kT)) * kC + cb + col] = v + sb2[col];
      }
      __syncthreads();
      setflag(FL, tid, bid, s + 1);
    }
  }
}

extern "C" void kernel_launch(void* const* d_in, const int* in_sizes, int n_in,
                              void* d_out, int out_size, void* d_ws, size_t ws_size,
                              hipStream_t stream) {
  (void)in_sizes; (void)n_in; (void)out_size; (void)ws_size;
  const float* x      = (const float*)d_in[0];
  const int*   lens   = (const int*)  d_in[1];
  const float* W_dg1  = (const float*)d_in[3];
  const float* b_dg1  = (const float*)d_in[4];
  const float* W_dg2  = (const float*)d_in[5];
  const float* b_dg2  = (const float*)d_in[6];
  const float* W_e1   = (const float*)d_in[7];
  const float* b_e1   = (const float*)d_in[8];
  const float* W_e2   = (const float*)d_in[9];
  const float* b_e2   = (const float*)d_in[10];
  const float* W_ih   = (const float*)d_in[11];
  const float* b_ih   = (const float*)d_in[12];
  const float* W_hh   = (const float*)d_in[13];
  const float* b_hh   = (const float*)d_in[14];
  const float* W_f1   = (const float*)d_in[15];
  const float* b_f1   = (const float*)d_in[16];
  const float* W_f2   = (const float*)d_in[17];
  const float* b_f2   = (const float*)d_in[18];

  hipMemsetAsync(d_ws, 0, WS_ZERO_BYTES, stream);
  delay_rnn<<<dim3(NB), dim3(NTHR), 0, stream>>>(
      x, lens, W_dg1, b_dg1, W_dg2, b_dg2, W_e1, b_e1, W_e2, b_e2,
      W_ih, b_ih, W_hh, b_hh, W_f1, b_f1, W_f2, b_f2,
      (float*)d_out, (float*)d_ws);
}